// Round 16
// baseline (2290.848 us; speedup 1.0000x reference)
//
#include <hip/hip_runtime.h>
#include <hip/hip_bf16.h>
#include <hip/hip_fp16.h>

using half_t = _Float16;
typedef __attribute__((ext_vector_type(8))) _Float16 f16x8;  // 8 fp16 = 4 VGPRs (MFMA frag)
typedef __attribute__((ext_vector_type(4))) _Float16 f16x4;
typedef __attribute__((ext_vector_type(4))) float f32x4;

#define LN_EPS 1e-5f

// async global->LDS, 16B per lane. gptr is PER-LANE, ldsbase is wave-uniform;
// HW writes ldsbase + lane*16.  [m97/m173 pattern]
__device__ inline void gll16(const void* g, void* ldsbase) {
    __builtin_amdgcn_global_load_lds(
        (const __attribute__((address_space(1))) void*)g,
        (__attribute__((address_space(3))) void*)ldsbase, 16, 0, 0);
}

// ---------------------------------------------------------------------------
// Block-per-row LN-LSTM cell: 256 thr, 4 contiguous elems/thread, LDS reduce.
// At final step writes h (fp32) and c (fp32) straight into d_out slots.
// ---------------------------------------------------------------------------
__device__ inline float block_sum(float v, float* sred) {
    #pragma unroll
    for (int off = 32; off; off >>= 1) v += __shfl_down(v, off, 64);
    __syncthreads();
    if ((threadIdx.x & 63) == 0) sred[threadIdx.x >> 6] = v;
    __syncthreads();
    return sred[0] + sred[1] + sred[2] + sred[3];
}

__device__ inline void cell_block(
    int b, const half_t* __restrict__ preA, const half_t* __restrict__ preB,
    const float* __restrict__ bias,
    float* __restrict__ cst, half_t* __restrict__ hs,
    float* __restrict__ hf, float* __restrict__ cf, bool final_step)
{
    __shared__ float sred[4];
    const int t = threadIdx.x;
    const int hi = t * 4;
    const size_t pb = (size_t)b * 4096 + hi;
    const size_t cb = (size_t)b * 1024 + hi;

    float pre[4][4];
    #pragma unroll
    for (int g = 0; g < 4; ++g) {
        f16x4 a4 = *(const f16x4*)&preA[pb + g*1024];
        f16x4 v4 = *(const f16x4*)&preB[pb + g*1024];
        float4 bs = *(const float4*)&bias[g*1024 + hi];
        pre[g][0] = (float)a4[0] + (float)v4[0] + bs.x;
        pre[g][1] = (float)a4[1] + (float)v4[1] + bs.y;
        pre[g][2] = (float)a4[2] + (float)v4[2] + bs.z;
        pre[g][3] = (float)a4[3] + (float)v4[3] + bs.w;
    }
    float4 c4 = *(const float4*)&cst[cb];
    float co[4] = {c4.x, c4.y, c4.z, c4.w};

    float cn[4], og[4], s = 0.f;
    #pragma unroll
    for (int j = 0; j < 4; ++j) {
        float ig = 1.f / (1.f + expf(-pre[0][j]));
        float fg = 1.f / (1.f + expf(-pre[1][j]));
        og[j]    = 1.f / (1.f + expf(-pre[2][j]));
        float ct = tanhf(pre[3][j]);
        cn[j] = fg * co[j] + ig * ct;
        s += cn[j];
    }
    float mu  = block_sum(s, sred) * (1.f/1024.f);
    float vs = 0.f;
    #pragma unroll
    for (int j = 0; j < 4; ++j) { float d = cn[j] - mu; vs += d*d; }
    float var = block_sum(vs, sred) * (1.f/1024.f);
    float rs  = rsqrtf(var + LN_EPS);

    float4 cw, hw; f16x4 h16w;
    #pragma unroll
    for (int j = 0; j < 4; ++j) {
        float cv = (cn[j] - mu) * rs;
        float hv = og[j] * tanhf(cv);
        ((float*)&cw)[j] = cv;
        ((float*)&hw)[j] = hv;
        h16w[j] = (half_t)hv;
    }
    *(float4*)&cst[cb] = cw;
    *(f16x4*)&hs[cb]   = h16w;
    if (final_step) {
        *(float4*)&hf[cb] = hw;
        *(float4*)&cf[cb] = cw;
    }
}

// cells(t): blocks 0..511 -> cell1(t) row b; 512..1023 -> cell2(t-1) row b-512.
__global__ __launch_bounds__(256) void cells_kernel(
    const half_t* __restrict__ preA1, const half_t* __restrict__ preB1,
    const half_t* __restrict__ preA2, const half_t* __restrict__ preB2,
    const float* __restrict__ b1x, const float* __restrict__ b2,
    float* __restrict__ c0, float* __restrict__ c1,
    half_t* __restrict__ h0s, half_t* __restrict__ h1s,
    float* __restrict__ out, int st)
{
    const int NSZ = 512 * 1024;
    const int blk = blockIdx.x;
    if (blk < 512) {
        cell_block(blk, preA1, preB1, b1x, c0, h0s,
                   out + NSZ, out + 3*NSZ, st == 63);
    } else {
        if (st == 0) return;
        cell_block(blk - 512, preA2, preB2, b2, c1, h1s,
                   nullptr, nullptr, false);
    }
}

// final cell2(63): h1 -> out[2*NSZ), c1 -> out[4*NSZ)
__global__ __launch_bounds__(256) void cells_final(
    const half_t* __restrict__ preA2, const half_t* __restrict__ preB2,
    const float* __restrict__ b2,
    float* __restrict__ c1, half_t* __restrict__ h1s, float* __restrict__ out)
{
    const int NSZ = 512 * 1024;
    cell_block(blockIdx.x, preA2, preB2, b2, c1, h1s,
               out + 2*NSZ, out + 4*NSZ, true);
}

// ---------------------------------------------------------------------------
// gemms(t): 1024 WGs, tile 64(M) x 128(N), BK=64, LDS 48 KB -> 3 WG/CU.
// Decode: ylo = wg&7 (XCD pin); r = wg>>3: x' = r&7 (64-row block),
//   yhi = (r>>3)&3, z = r>>5  -> same-CU resident sets {r, r+32, r+64}
//   get DIFFERENT z (heavy/light mixed; no CU strands on two z3 WGs).
//   z0: preA2(t)   = h0(t)   @ wx2^T            (K=1024, 16 K-tiles)
//   z1: preB2(t)   = h1(t-1) @ wh2^T            (K=1024)
//   z2: preB1(t+1) = h0(t)   @ wh1^T            (K=1024)
//   z3: preA1(t+1) = obs(t+1) @ W1x^T           (K=512, 8 K-tiles; A fp32
//       reg-staged + cvt + late ds_write; skipped st==63; st==-1 runs z3 only)
// 4 waves, wave tile 32x64 (acc 2x4). 2-phase pipeline, XOR swizzle.
// ---------------------------------------------------------------------------
__global__ __launch_bounds__(256, 3) void step_gemm4(
    const float* __restrict__ obsF,
    const half_t* __restrict__ W1x, const half_t* __restrict__ wx2c,
    const half_t* __restrict__ wh1t, const half_t* __restrict__ wh2t,
    half_t* __restrict__ preA1, half_t* __restrict__ preA2,
    half_t* __restrict__ preB1, half_t* __restrict__ preB2,
    const half_t* __restrict__ h0s, const half_t* __restrict__ h1s, int st)
{
    __shared__ __align__(16) unsigned char sA[2][8192];    // 64 rows x 64 K fp16
    __shared__ __align__(16) unsigned char sB[2][16384];   // 128 rows x 64 K fp16

    const int wg = blockIdx.x;
    const int ylo = wg & 7;
    int r = wg >> 3;
    const int x   = r & 7;
    const int yhi = (r >> 3) & 3;
    const int z   = r >> 5;
    const int y   = ylo + 8 * yhi;       // 0..31

    const bool zx = (z == 3);
    if (zx && st == 63) return;          // no t+1
    if (st < 0 && !zx) return;           // prologue: z3 only

    const half_t* A; const half_t* B; half_t* C; size_t lda, ldb; int nkt;
    const float* Af = nullptr;
    if (z == 0)      { A = h0s; lda = 1024; B = wx2c; ldb = 1024; C = preA2; nkt = 16; }
    else if (z == 1) { A = h1s; lda = 1024; B = wh2t; ldb = 1024; C = preB2; nkt = 16; }
    else if (z == 2) { A = h0s; lda = 1024; B = wh1t; ldb = 1024; C = preB1; nkt = 16; }
    else { Af = obsF + (size_t)(st+1) * 512; A = nullptr; lda = 32768;
           B = W1x; ldb = 512; C = preA1; nkt = 8; }

    const int t = threadIdx.x, l = t & 63, w = t >> 6;
    const int wr = (w >> 1) * 32, wc = (w & 1) * 64;
    const int rowbase = x * 64, colbase = y * 128;

    // staging geometry: A 512 slots (2/thread), B 1024 slots (4/thread)
    int srA[2], scA[2], srB[4], scB[4];
    #pragma unroll
    for (int i = 0; i < 2; ++i) {
        int s = (w*2 + i)*64 + l;
        srA[i] = s >> 3; scA[i] = ((s & 7) ^ (srA[i] & 7)) * 8;
    }
    #pragma unroll
    for (int i = 0; i < 4; ++i) {
        int s = (w*4 + i)*64 + l;
        srB[i] = s >> 3; scB[i] = ((s & 7) ^ (srB[i] & 7)) * 8;
    }

    f32x4 acc[2][4];
    #pragma unroll
    for (int m = 0; m < 2; ++m)
        #pragma unroll
        for (int n = 0; n < 4; ++n) acc[m][n] = (f32x4)(0.f);

    float4 fv[4];                        // z3: raw fp32 A in regs (late cvt+write)
    auto stageB = [&](int kt, int buf) {
        const int ko = kt * 64;
        #pragma unroll
        for (int i = 0; i < 4; ++i)
            gll16(B + (size_t)(colbase+srB[i])*ldb + ko + scB[i], &sB[buf][(w*4+i)*1024]);
    };
    auto stageA_h = [&](int kt, int buf) {
        const int ko = kt * 64;
        #pragma unroll
        for (int i = 0; i < 2; ++i)
            gll16(A + (size_t)(rowbase+srA[i])*lda + ko + scA[i], &sA[buf][(w*2+i)*1024]);
    };
    auto loadA_f = [&](int kt) {         // issue fp32 loads (plain -> compiler waits)
        const int ko = kt * 64;
        #pragma unroll
        for (int i = 0; i < 2; ++i) {
            const float* p = Af + (size_t)(rowbase+srA[i])*lda + ko + scA[i];
            fv[2*i]   = *(const float4*)p;
            fv[2*i+1] = *(const float4*)(p + 4);
        }
    };
    auto writeA_f = [&](int buf) {       // cvt + ds_write (after compute)
        #pragma unroll
        for (int i = 0; i < 2; ++i) {
            union { uint4 v; half_t h[8]; } rr;
            rr.h[0]=(half_t)fv[2*i].x;   rr.h[1]=(half_t)fv[2*i].y;
            rr.h[2]=(half_t)fv[2*i].z;   rr.h[3]=(half_t)fv[2*i].w;
            rr.h[4]=(half_t)fv[2*i+1].x; rr.h[5]=(half_t)fv[2*i+1].y;
            rr.h[6]=(half_t)fv[2*i+1].z; rr.h[7]=(half_t)fv[2*i+1].w;
            *(uint4*)&sA[buf][((w*2+i)*64 + l)*16] = rr.v;
        }
    };

    // prologue: stage K-tile 0
    stageB(0, 0);
    if (zx) { loadA_f(0); writeA_f(0); }
    else    stageA_h(0, 0);

    for (int kt = 0; kt < nkt; ++kt) {
        const int buf = kt & 1;
        __syncthreads();                 // vmcnt(0)+lgkm: buf ready; WAR-safe for buf^1
        const bool more = (kt + 1 < nkt);
        if (more) {
            stageB(kt + 1, buf ^ 1);
            if (zx) loadA_f(kt + 1);
            else    stageA_h(kt + 1, buf ^ 1);
        }
        #pragma unroll
        for (int kk = 0; kk < 2; ++kk) {
            const int chunk = kk*4 + (l >> 4);
            f16x8 bfr[4];
            #pragma unroll
            for (int n = 0; n < 4; ++n) {
                int rowb = wc + n*16 + (l & 15);
                bfr[n] = *(const f16x8*)&sB[buf][rowb*128 + ((chunk ^ (rowb & 7)) << 4)];
            }
            #pragma unroll
            for (int m = 0; m < 2; ++m) {
                int rowa = wr + m*16 + (l & 15);
                f16x8 af = *(const f16x8*)&sA[buf][rowa*128 + ((chunk ^ (rowa & 7)) << 4)];
                #pragma unroll
                for (int n = 0; n < 4; ++n)
                    acc[m][n] = __builtin_amdgcn_mfma_f32_16x16x32_f16(af, bfr[n], acc[m][n], 0, 0, 0);
            }
        }
        if (zx && more) writeA_f(buf ^ 1);   // loads aged a full compute phase
    }

    // epilogue: C/D layout col = lane&15, row = (lane>>4)*4 + reg  [m89/m91]
    #pragma unroll
    for (int m = 0; m < 2; ++m) {
        int row0 = rowbase + wr + m*16 + (l >> 4)*4;
        #pragma unroll
        for (int n = 0; n < 4; ++n) {
            int col = colbase + wc + n*16 + (l & 15);
            #pragma unroll
            for (int r2 = 0; r2 < 4; ++r2)
                C[(size_t)(row0+r2)*4096 + col] = (half_t)acc[m][n][r2];
        }
    }
}

struct GArgs {
    const half_t* A; const half_t* B; const float* bias; void* C;
    int lda, ldb, K, ldc, outhalf;
};

// ---------------------------------------------------------------------------
// Multi-set fp16 GEMM (prologue / fc2): up to 3 independent C=A*B^T.
// rowpin=1 pins x%8 to XCD (use when A is the large operand).
// ---------------------------------------------------------------------------
__global__ __launch_bounds__(256) void gemm_ms(GArgs g0, GArgs g1, GArgs g2,
                                               int gx, int gy, int gz, int rowpin)
{
    const int d = blockIdx.x;
    int x, y, z;
    if (rowpin) {
        const int xlo = d & 7;
        int r = d >> 3;
        y = r % gy;  r /= gy;
        z = r % gz;
        x = xlo + 8 * (r / gz);
    } else {
        const int ylo = d & 7;
        int r = d >> 3;
        x = r % gx;  r /= gx;
        z = r % gz;
        y = ylo + 8 * (r / gz);
    }

    const GArgs g = (z == 0) ? g0 : (z == 1 ? g1 : g2);

    __shared__ __align__(16) unsigned char sA[2][16384];
    __shared__ __align__(16) unsigned char sB[2][16384];

    const int t  = threadIdx.x;
    const int l  = t & 63;
    const int w  = t >> 6;
    const int wr = (w >> 1) * 64;
    const int wc = (w & 1)  * 64;
    const int rowbase = x * 128;
    const int colbase = y * 128;

    f32x4 acc[4][4];
    #pragma unroll
    for (int m = 0; m < 4; ++m)
        #pragma unroll
        for (int n = 0; n < 4; ++n) acc[m][n] = (f32x4)(0.f);

    int srow[4], sch[4];
    #pragma unroll
    for (int i = 0; i < 4; ++i) {
        int s = (w*4 + i)*64 + l;
        srow[i] = s >> 3;
        sch[i]  = ((s & 7) ^ (srow[i] & 7)) * 8;
    }

    const int nkt = g.K >> 6;

    auto stage = [&](int kt, int buf) {
        const int ko = kt * 64;
        #pragma unroll
        for (int i = 0; i < 4; ++i) {
            gll16(g.A + (size_t)(rowbase+srow[i])*g.lda + ko + sch[i], &sA[buf][(w*4+i)*1024]);
            gll16(g.B + (size_t)(colbase+srow[i])*g.ldb + ko + sch[i], &sB[buf][(w*4+i)*1024]);
        }
    };

    stage(0, 0);
    for (int kt = 0; kt < nkt; ++kt) {
        const int buf = kt & 1;
        __syncthreads();
        if (kt + 1 < nkt) stage(kt + 1, buf ^ 1);
        #pragma unroll
        for (int kk = 0; kk < 2; ++kk) {
            const int chunk = kk*4 + (l >> 4);
            f16x8 bfr[4];
            #pragma unroll
            for (int n = 0; n < 4; ++n) {
                int rowb = wc + n*16 + (l & 15);
                bfr[n] = *(const f16x8*)&sB[buf][rowb*128 + ((chunk ^ (rowb & 7)) << 4)];
            }
            #pragma unroll
            for (int m = 0; m < 4; ++m) {
                int rowa = wr + m*16 + (l & 15);
                f16x8 af = *(const f16x8*)&sA[buf][rowa*128 + ((chunk ^ (rowa & 7)) << 4)];
                #pragma unroll
                for (int n = 0; n < 4; ++n)
                    acc[m][n] = __builtin_amdgcn_mfma_f32_16x16x32_f16(af, bfr[n], acc[m][n], 0, 0, 0);
            }
        }
    }

    #pragma unroll
    for (int m = 0; m < 4; ++m) {
        int row0 = rowbase + wr + m*16 + (l >> 4)*4;
        #pragma unroll
        for (int n = 0; n < 4; ++n) {
            int col = colbase + wc + n*16 + (l & 15);
            float bv = g.bias ? g.bias[col] : 0.f;
            #pragma unroll
            for (int r2 = 0; r2 < 4; ++r2) {
                float v = acc[m][n][r2] + bv;
                if (g.outhalf) ((half_t*)g.C)[(size_t)(row0+r2)*g.ldc + col] = (half_t)v;
                else           ((float*)g.C)[(size_t)(row0+r2)*g.ldc + col] = v;
            }
        }
    }
}

// ---------------------------------------------------------------------------
__global__ __launch_bounds__(256) void transpose_wh_cvt(
    const float* __restrict__ wh1, const float* __restrict__ wh2,
    half_t* __restrict__ o1, half_t* __restrict__ o2)
{
    __shared__ float tile[64][65];
    const int z = blockIdx.z;
    const float* src = (z < 4 ? wh1 : wh2) + (size_t)(z & 3) * 1024 * 1024;
    half_t*      dst = (z < 4 ? o1  : o2 ) + (size_t)(z & 3) * 1024 * 1024;
    const int kb = blockIdx.x * 64, nb = blockIdx.y * 64;
    const int t = threadIdx.x;
    #pragma unroll
    for (int i = 0; i < 16; ++i) {
        int idx = t + i*256, r = idx >> 6, c = idx & 63;
        tile[r][c] = src[(size_t)(kb + r)*1024 + nb + c];
    }
    __syncthreads();
    #pragma unroll
    for (int i = 0; i < 16; ++i) {
        int idx = t + i*256, r = idx >> 6, c = idx & 63;
        dst[(size_t)(nb + r)*1024 + kb + c] = (half_t)tile[c][r];
    }
}

// fc1_w (fp32 [1024][512]) -> fc1t (fp16 [512][1024])  (transpose + convert)
__global__ __launch_bounds__(256) void transpose_fc1(
    const float* __restrict__ fc1_w, half_t* __restrict__ fc1t)
{
    __shared__ float tile[64][65];
    const int hb = blockIdx.x * 64, ob = blockIdx.y * 64;   // grid (16, 8)
    const int t = threadIdx.x;
    #pragma unroll
    for (int i = 0; i < 16; ++i) {
        int idx = t + i*256, r = idx >> 6, c = idx & 63;
        tile[r][c] = fc1_w[(size_t)(hb + r)*512 + ob + c];
    }
    __syncthreads();
    #pragma unroll
    for (int i = 0; i < 16; ++i) {
        int idx = t + i*256, r = idx >> 6, c = idx & 63;
        fc1t[(size_t)(ob + r)*1024 + hb + c] = (half_t)tile[c][r];
    }
}

// b1x[j] = b1[j] + dot(wx1[j,:], fc1_b)   (fp32, j < 4096; one block per j)
__global__ __launch_bounds__(256) void fold_b1(
    const float* __restrict__ wx1, const float* __restrict__ fc1_b,
    const float* __restrict__ b1, float* __restrict__ b1x)
{
    __shared__ float sred[4];
    const int j = blockIdx.x, t = threadIdx.x;
    float4 wv = *(const float4*)&wx1[(size_t)j*1024 + t*4];
    float4 bv = *(const float4*)&fc1_b[t*4];
    float s = wv.x*bv.x + wv.y*bv.y + wv.z*bv.z + wv.w*bv.w;
    float tot = block_sum(s, sred);
    if (t == 0) b1x[j] = b1[j] + tot;
}

__global__ __launch_bounds__(256) void cvt_f32_f16(
    const float* __restrict__ in, half_t* __restrict__ out, int n8)
{
    int i = blockIdx.x * 256 + threadIdx.x;
    if (i >= n8) return;
    float4 lo = ((const float4*)in)[2*i];
    float4 hi = ((const float4*)in)[2*i + 1];
    union { uint4 v; half_t h[8]; } r;
    r.h[0]=(half_t)lo.x; r.h[1]=(half_t)lo.y; r.h[2]=(half_t)lo.z; r.h[3]=(half_t)lo.w;
    r.h[4]=(half_t)hi.x; r.h[5]=(half_t)hi.y; r.h[6]=(half_t)hi.z; r.h[7]=(half_t)hi.w;
    ((uint4*)out)[i] = r.v;
}

extern "C" void kernel_launch(void* const* d_in, const int* in_sizes, int n_in,
                              void* d_out, int out_size, void* d_ws, size_t ws_size,
                              hipStream_t stream)
{
    const float* obs   = (const float*)d_in[0];
    const float* fc1_w = (const float*)d_in[1];
    const float* fc1_b = (const float*)d_in[2];
    const float* wx1   = (const float*)d_in[3];
    const float* wh1   = (const float*)d_in[4];
    const float* b1    = (const float*)d_in[5];
    const float* wx2   = (const float*)d_in[6];
    const float* wh2   = (const float*)d_in[7];
    const float* b2    = (const float*)d_in[8];
    const float* fc2_w = (const float*)d_in[9];
    const float* fc2_b = (const float*)d_in[10];
    float* out = (float*)d_out;

    char* ws = (char*)d_ws;
    size_t off = 0;
    auto carve = [&](size_t bytes) -> char* {
        char* p = ws + off; off += (bytes + 255) & ~(size_t)255; return p;
    };
    half_t* wx1c  = (half_t*)carve((size_t)4096*1024*2);    //  8.4 MB
    half_t* wh1t  = (half_t*)carve((size_t)4096*1024*2);
    half_t* wx2c  = (half_t*)carve((size_t)4096*1024*2);
    half_t* wh2t  = (half_t*)carve((size_t)4096*1024*2);
    half_t* fc1t  = (half_t*)carve((size_t)512*1024*2);     //  1.0 MB
    half_t* W1x   = (half_t*)carve((size_t)4096*512*2);     //  4.2 MB
    half_t* fc2c  = (half_t*)carve((size_t)1024*1024*2);
    float*  b1x   = (float*) carve((size_t)4096*4);
    half_t* preA1 = (half_t*)carve((size_t)512*4096*2);     //  4.2 MB
    half_t* preA2 = (half_t*)carve((size_t)512*4096*2);
    half_t* preB1 = (half_t*)carve((size_t)512*4096*2);
    half_t* preB2 = (half_t*)carve((size_t)512*4096*2);
    half_t* h0s   = (half_t*)carve((size_t)512*1024*2);
    half_t* h1s   = (half_t*)carve((size_t)512*1024*2);
    float*  c0    = (float*) carve((size_t)512*1024*4);
    float*  c1    = (float*) carve((size_t)512*1024*4);

    hipMemsetAsync(h1s, 0, (size_t)512*1024*2, stream);     // h1(-1)=0 for z1@st0
    hipMemsetAsync(c0,  0, (size_t)512*1024*4, stream);
    hipMemsetAsync(c1,  0, (size_t)512*1024*4, stream);
    hipMemsetAsync(preB1, 0, (size_t)512*4096*2, stream);   // h0(-1)=0

    // one-time conversions + fc1 fold
    cvt_f32_f16<<<2048, 256, 0, stream>>>(wx1,   wx1c,  4*1024*1024/8);
    cvt_f32_f16<<<2048, 256, 0, stream>>>(wx2,   wx2c,  4*1024*1024/8);
    cvt_f32_f16<<<512,  256, 0, stream>>>(fc2_w, fc2c,  1024*1024/8);
    transpose_wh_cvt<<<dim3(16,16,8), 256, 0, stream>>>(wh1, wh2, wh1t, wh2t);
    transpose_fc1<<<dim3(16,8), 256, 0, stream>>>(fc1_w, fc1t);
    fold_b1<<<4096, 256, 0, stream>>>(wx1, fc1_b, b1, b1x);

    GArgs Z{};
    auto ga = [](const half_t* A, int lda, const half_t* B, int ldb, int K,
                 const float* bias, void* C, int ldc, int outhalf) {
        GArgs g; g.A=A; g.B=B; g.bias=bias; g.C=C;
        g.lda=lda; g.ldb=ldb; g.K=K; g.ldc=ldc; g.outhalf=outhalf; return g;
    };

    // W1x[4096][512] = wx1c @ fc1t^T  (M=4096, N=512, K=1024; A large -> rowpin)
    gemm_ms<<<128, 256, 0, stream>>>(
        ga(wx1c, 1024, fc1t, 1024, 1024, nullptr, W1x, 512, 1), Z, Z, 32, 4, 1, 1);
    // preA1(0) = obs(0) @ W1x^T  (st=-1: z3-only pass of the step kernel)
    step_gemm4<<<1024, 256, 0, stream>>>(
        obs, W1x, wx2c, wh1t, wh2t,
        preA1, preA2, preB1, preB2, h0s, h1s, -1);

    for (int st = 0; st < 64; ++st) {
        cells_kernel<<<1024, 256, 0, stream>>>(
            preA1, preB1, preA2, preB2, b1x, b2,
            c0, c1, h0s, h1s, out, st);
        step_gemm4<<<1024, 256, 0, stream>>>(
            obs, W1x, wx2c, wh1t, wh2t,
            preA1, preA2, preB1, preB2, h0s, h1s, st);
    }
    cells_final<<<512, 256, 0, stream>>>(preA2, preB2, b2, c1, h1s, out);

    // fc2: logit = h1 @ fc2_w^T + fc2_b -> d_out[0 : 512*1024) fp32
    gemm_ms<<<4*8, 256, 0, stream>>>(
        ga(h1s, 1024, fc2c, 1024, 1024, fc2_b, out, 1024, 0), Z, Z, 4, 8, 1, 0);
}

// Round 17
// 2050.699 us; speedup vs baseline: 1.1171x; 1.1171x over previous
//
#include <hip/hip_runtime.h>
#include <hip/hip_bf16.h>
#include <hip/hip_fp16.h>

using half_t = _Float16;
typedef __attribute__((ext_vector_type(8))) _Float16 f16x8;  // 8 fp16 = 4 VGPRs (MFMA frag)
typedef __attribute__((ext_vector_type(4))) _Float16 f16x4;
typedef __attribute__((ext_vector_type(4))) float f32x4;

#define LN_EPS 1e-5f

// async global->LDS, 16B per lane. gptr is PER-LANE, ldsbase is wave-uniform;
// HW writes ldsbase + lane*16.  [m97/m173 pattern]
__device__ inline void gll16(const void* g, void* ldsbase) {
    __builtin_amdgcn_global_load_lds(
        (const __attribute__((address_space(1))) void*)g,
        (__attribute__((address_space(3))) void*)ldsbase, 16, 0, 0);
}

// ---------------------------------------------------------------------------
// Block-per-row LN-LSTM cell: 256 thr, 4 contiguous elems/thread, LDS reduce.
// At final step writes h (fp32) and c (fp32) straight into d_out slots.
// ---------------------------------------------------------------------------
__device__ inline float block_sum(float v, float* sred) {
    #pragma unroll
    for (int off = 32; off; off >>= 1) v += __shfl_down(v, off, 64);
    __syncthreads();
    if ((threadIdx.x & 63) == 0) sred[threadIdx.x >> 6] = v;
    __syncthreads();
    return sred[0] + sred[1] + sred[2] + sred[3];
}

__device__ inline void cell_block(
    int b, const half_t* __restrict__ preA, const half_t* __restrict__ preB,
    const float* __restrict__ bias,
    float* __restrict__ cst, half_t* __restrict__ hs,
    float* __restrict__ hf, float* __restrict__ cf, bool final_step)
{
    __shared__ float sred[4];
    const int t = threadIdx.x;
    const int hi = t * 4;
    const size_t pb = (size_t)b * 4096 + hi;
    const size_t cb = (size_t)b * 1024 + hi;

    float pre[4][4];
    #pragma unroll
    for (int g = 0; g < 4; ++g) {
        f16x4 a4 = *(const f16x4*)&preA[pb + g*1024];
        f16x4 v4 = *(const f16x4*)&preB[pb + g*1024];
        float4 bs = *(const float4*)&bias[g*1024 + hi];
        pre[g][0] = (float)a4[0] + (float)v4[0] + bs.x;
        pre[g][1] = (float)a4[1] + (float)v4[1] + bs.y;
        pre[g][2] = (float)a4[2] + (float)v4[2] + bs.z;
        pre[g][3] = (float)a4[3] + (float)v4[3] + bs.w;
    }
    float4 c4 = *(const float4*)&cst[cb];
    float co[4] = {c4.x, c4.y, c4.z, c4.w};

    float cn[4], og[4], s = 0.f;
    #pragma unroll
    for (int j = 0; j < 4; ++j) {
        float ig = 1.f / (1.f + expf(-pre[0][j]));
        float fg = 1.f / (1.f + expf(-pre[1][j]));
        og[j]    = 1.f / (1.f + expf(-pre[2][j]));
        float ct = tanhf(pre[3][j]);
        cn[j] = fg * co[j] + ig * ct;
        s += cn[j];
    }
    float mu  = block_sum(s, sred) * (1.f/1024.f);
    float vs = 0.f;
    #pragma unroll
    for (int j = 0; j < 4; ++j) { float d = cn[j] - mu; vs += d*d; }
    float var = block_sum(vs, sred) * (1.f/1024.f);
    float rs  = rsqrtf(var + LN_EPS);

    float4 cw, hw; f16x4 h16w;
    #pragma unroll
    for (int j = 0; j < 4; ++j) {
        float cv = (cn[j] - mu) * rs;
        float hv = og[j] * tanhf(cv);
        ((float*)&cw)[j] = cv;
        ((float*)&hw)[j] = hv;
        h16w[j] = (half_t)hv;
    }
    *(float4*)&cst[cb] = cw;
    *(f16x4*)&hs[cb]   = h16w;
    if (final_step) {
        *(float4*)&hf[cb] = hw;
        *(float4*)&cf[cb] = cw;
    }
}

// cells(t): blocks 0..511 -> cell1(t) row b; 512..1023 -> cell2(t-1) row b-512.
__global__ __launch_bounds__(256) void cells_kernel(
    const half_t* __restrict__ preA1, const half_t* __restrict__ preB1,
    const half_t* __restrict__ preA2, const half_t* __restrict__ preB2,
    const float* __restrict__ b1x, const float* __restrict__ b2,
    float* __restrict__ c0, float* __restrict__ c1,
    half_t* __restrict__ h0s, half_t* __restrict__ h1s,
    float* __restrict__ out, int st)
{
    const int NSZ = 512 * 1024;
    const int blk = blockIdx.x;
    if (blk < 512) {
        cell_block(blk, preA1, preB1, b1x, c0, h0s,
                   out + NSZ, out + 3*NSZ, st == 63);
    } else {
        if (st == 0) return;
        cell_block(blk - 512, preA2, preB2, b2, c1, h1s,
                   nullptr, nullptr, false);
    }
}

// final cell2(63): h1 -> out[2*NSZ), c1 -> out[4*NSZ)
__global__ __launch_bounds__(256) void cells_final(
    const half_t* __restrict__ preA2, const half_t* __restrict__ preB2,
    const float* __restrict__ b2,
    float* __restrict__ c1, half_t* __restrict__ h1s, float* __restrict__ out)
{
    const int NSZ = 512 * 1024;
    cell_block(blockIdx.x, preA2, preB2, b2, c1, h1s,
               out + 2*NSZ, out + 4*NSZ, true);
}

// ---------------------------------------------------------------------------
// gemms(t): 512 WGs. wg = ylo + 8*(x + 4*(z + 4*yhi)):
//   z0: preA2(t)   = h0(t)   @ wx2^T            (K=1024)
//   z1: preB2(t)   = h1(t-1) @ wh2^T            (K=1024)
//   z2: preB1(t+1) = h0(t)   @ wh1^T            (K=1024)
//   z3: preA1(t+1) = obs(t+1) @ W1x^T           (K=512; fc1 folded into W1x;
//       A read as fp32 DIRECTLY from obs, reg-staged + cvt + late ds_write;
//       skipped at st==63; st==-1 prologue runs z3 only)
// y%8 == dispatch%8 -> weight panels XCD-pinned across all 64 steps.
// ---------------------------------------------------------------------------
__global__ __launch_bounds__(256, 2) void step_gemm4(
    const float* __restrict__ obsF,
    const half_t* __restrict__ W1x, const half_t* __restrict__ wx2c,
    const half_t* __restrict__ wh1t, const half_t* __restrict__ wh2t,
    half_t* __restrict__ preA1, half_t* __restrict__ preA2,
    half_t* __restrict__ preB1, half_t* __restrict__ preB2,
    const half_t* __restrict__ h0s, const half_t* __restrict__ h1s, int st)
{
    __shared__ __align__(16) unsigned char sA[2][16384];
    __shared__ __align__(16) unsigned char sB[2][16384];

    const int wg = blockIdx.x;
    const int ylo = wg & 7;
    int r = wg >> 3;
    const int x = r & 3; r >>= 2;
    const int z = r & 3; r >>= 2;
    const int y = ylo + 8 * r;

    const bool zx = (z == 3);
    if (zx && st == 63) return;          // no t+1
    if (st < 0 && !zx) return;           // prologue: z3 only

    const half_t* A; const half_t* B; half_t* C; size_t lda, ldb; int nkt;
    const float* Af = nullptr;
    if (z == 0)      { A = h0s; lda = 1024; B = wx2c; ldb = 1024; C = preA2; nkt = 16; }
    else if (z == 1) { A = h1s; lda = 1024; B = wh2t; ldb = 1024; C = preB2; nkt = 16; }
    else if (z == 2) { A = h0s; lda = 1024; B = wh1t; ldb = 1024; C = preB1; nkt = 16; }
    else { Af = obsF + (size_t)(st+1) * 512; A = nullptr; lda = 32768;
           B = W1x; ldb = 512; C = preA1; nkt = 8; }

    const int t = threadIdx.x, l = t & 63, w = t >> 6;
    const int wr = (w >> 1) * 64, wc = (w & 1) * 64;
    const int rowbase = x * 128, colbase = y * 128;

    int srow[4], sch[4];
    #pragma unroll
    for (int i = 0; i < 4; ++i) {
        int s = (w*4 + i)*64 + l;
        srow[i] = s >> 3;
        sch[i]  = ((s & 7) ^ (srow[i] & 7)) * 8;
    }

    f32x4 acc[4][4];
    #pragma unroll
    for (int m = 0; m < 4; ++m)
        #pragma unroll
        for (int n = 0; n < 4; ++n) acc[m][n] = (f32x4)(0.f);

    float4 fv[8];                        // z3: raw fp32 A in regs (late cvt+write)
    auto stageB = [&](int kt, int buf) {
        const int ko = kt * 64;
        #pragma unroll
        for (int i = 0; i < 4; ++i)
            gll16(B + (size_t)(colbase+srow[i])*ldb + ko + sch[i], &sB[buf][(w*4+i)*1024]);
    };
    auto stageA_h = [&](int kt, int buf) {
        const int ko = kt * 64;
        #pragma unroll
        for (int i = 0; i < 4; ++i)
            gll16(A + (size_t)(rowbase+srow[i])*lda + ko + sch[i], &sA[buf][(w*4+i)*1024]);
    };
    auto loadA_f = [&](int kt) {         // issue fp32 loads (plain -> compiler waits)
        const int ko = kt * 64;
        #pragma unroll
        for (int i = 0; i < 4; ++i) {
            const float* p = Af + (size_t)(rowbase+srow[i])*lda + ko + sch[i];
            fv[2*i]   = *(const float4*)p;
            fv[2*i+1] = *(const float4*)(p + 4);
        }
    };
    auto writeA_f = [&](int buf) {       // cvt + ds_write (after compute)
        #pragma unroll
        for (int i = 0; i < 4; ++i) {
            union { uint4 v; half_t h[8]; } rr;
            rr.h[0]=(half_t)fv[2*i].x;   rr.h[1]=(half_t)fv[2*i].y;
            rr.h[2]=(half_t)fv[2*i].z;   rr.h[3]=(half_t)fv[2*i].w;
            rr.h[4]=(half_t)fv[2*i+1].x; rr.h[5]=(half_t)fv[2*i+1].y;
            rr.h[6]=(half_t)fv[2*i+1].z; rr.h[7]=(half_t)fv[2*i+1].w;
            *(uint4*)&sA[buf][((w*4+i)*64 + l)*16] = rr.v;
        }
    };

    // prologue: stage K-tile 0
    stageB(0, 0);
    if (zx) { loadA_f(0); writeA_f(0); }
    else    stageA_h(0, 0);

    for (int kt = 0; kt < nkt; ++kt) {
        const int buf = kt & 1;
        __syncthreads();                 // vmcnt(0)+lgkm: buf ready; WAR-safe for buf^1
        const bool more = (kt + 1 < nkt);
        if (more) {
            stageB(kt + 1, buf ^ 1);
            if (zx) loadA_f(kt + 1);
            else    stageA_h(kt + 1, buf ^ 1);
        }
        #pragma unroll
        for (int kk = 0; kk < 2; ++kk) {
            const int chunk = kk*4 + (l >> 4);
            f16x8 bfr[4];
            #pragma unroll
            for (int n = 0; n < 4; ++n) {
                int rowb = wc + n*16 + (l & 15);
                bfr[n] = *(const f16x8*)&sB[buf][rowb*128 + ((chunk ^ (rowb & 7)) << 4)];
            }
            #pragma unroll
            for (int m = 0; m < 4; ++m) {
                int rowa = wr + m*16 + (l & 15);
                f16x8 af = *(const f16x8*)&sA[buf][rowa*128 + ((chunk ^ (rowa & 7)) << 4)];
                #pragma unroll
                for (int n = 0; n < 4; ++n)
                    acc[m][n] = __builtin_amdgcn_mfma_f32_16x16x32_f16(af, bfr[n], acc[m][n], 0, 0, 0);
            }
        }
        if (zx && more) writeA_f(buf ^ 1);   // loads aged a full compute phase
    }

    // epilogue: C/D layout col = lane&15, row = (lane>>4)*4 + reg  [m89/m91]
    #pragma unroll
    for (int m = 0; m < 4; ++m) {
        int row0 = rowbase + wr + m*16 + (l >> 4)*4;
        #pragma unroll
        for (int n = 0; n < 4; ++n) {
            int col = colbase + wc + n*16 + (l & 15);
            #pragma unroll
            for (int r2 = 0; r2 < 4; ++r2)
                C[(size_t)(row0+r2)*4096 + col] = (half_t)acc[m][n][r2];
        }
    }
}

struct GArgs {
    const half_t* A; const half_t* B; const float* bias; void* C;
    int lda, ldb, K, ldc, outhalf;
};

// ---------------------------------------------------------------------------
// Multi-set fp16 GEMM (prologue / fc2): up to 3 independent C=A*B^T.
// rowpin=1 pins x%8 to XCD (use when A is the large operand).
// ---------------------------------------------------------------------------
__global__ __launch_bounds__(256) void gemm_ms(GArgs g0, GArgs g1, GArgs g2,
                                               int gx, int gy, int gz, int rowpin)
{
    const int d = blockIdx.x;
    int x, y, z;
    if (rowpin) {
        const int xlo = d & 7;
        int r = d >> 3;
        y = r % gy;  r /= gy;
        z = r % gz;
        x = xlo + 8 * (r / gz);
    } else {
        const int ylo = d & 7;
        int r = d >> 3;
        x = r % gx;  r /= gx;
        z = r % gz;
        y = ylo + 8 * (r / gz);
    }

    const GArgs g = (z == 0) ? g0 : (z == 1 ? g1 : g2);

    __shared__ __align__(16) unsigned char sA[2][16384];
    __shared__ __align__(16) unsigned char sB[2][16384];

    const int t  = threadIdx.x;
    const int l  = t & 63;
    const int w  = t >> 6;
    const int wr = (w >> 1) * 64;
    const int wc = (w & 1)  * 64;
    const int rowbase = x * 128;
    const int colbase = y * 128;

    f32x4 acc[4][4];
    #pragma unroll
    for (int m = 0; m < 4; ++m)
        #pragma unroll
        for (int n = 0; n < 4; ++n) acc[m][n] = (f32x4)(0.f);

    int srow[4], sch[4];
    #pragma unroll
    for (int i = 0; i < 4; ++i) {
        int s = (w*4 + i)*64 + l;
        srow[i] = s >> 3;
        sch[i]  = ((s & 7) ^ (srow[i] & 7)) * 8;
    }

    const int nkt = g.K >> 6;

    auto stage = [&](int kt, int buf) {
        const int ko = kt * 64;
        #pragma unroll
        for (int i = 0; i < 4; ++i) {
            gll16(g.A + (size_t)(rowbase+srow[i])*g.lda + ko + sch[i], &sA[buf][(w*4+i)*1024]);
            gll16(g.B + (size_t)(colbase+srow[i])*g.ldb + ko + sch[i], &sB[buf][(w*4+i)*1024]);
        }
    };

    stage(0, 0);
    for (int kt = 0; kt < nkt; ++kt) {
        const int buf = kt & 1;
        __syncthreads();
        if (kt + 1 < nkt) stage(kt + 1, buf ^ 1);
        #pragma unroll
        for (int kk = 0; kk < 2; ++kk) {
            const int chunk = kk*4 + (l >> 4);
            f16x8 bfr[4];
            #pragma unroll
            for (int n = 0; n < 4; ++n) {
                int rowb = wc + n*16 + (l & 15);
                bfr[n] = *(const f16x8*)&sB[buf][rowb*128 + ((chunk ^ (rowb & 7)) << 4)];
            }
            #pragma unroll
            for (int m = 0; m < 4; ++m) {
                int rowa = wr + m*16 + (l & 15);
                f16x8 af = *(const f16x8*)&sA[buf][rowa*128 + ((chunk ^ (rowa & 7)) << 4)];
                #pragma unroll
                for (int n = 0; n < 4; ++n)
                    acc[m][n] = __builtin_amdgcn_mfma_f32_16x16x32_f16(af, bfr[n], acc[m][n], 0, 0, 0);
            }
        }
    }

    #pragma unroll
    for (int m = 0; m < 4; ++m) {
        int row0 = rowbase + wr + m*16 + (l >> 4)*4;
        #pragma unroll
        for (int n = 0; n < 4; ++n) {
            int col = colbase + wc + n*16 + (l & 15);
            float bv = g.bias ? g.bias[col] : 0.f;
            #pragma unroll
            for (int r2 = 0; r2 < 4; ++r2) {
                float v = acc[m][n][r2] + bv;
                if (g.outhalf) ((half_t*)g.C)[(size_t)(row0+r2)*g.ldc + col] = (half_t)v;
                else           ((float*)g.C)[(size_t)(row0+r2)*g.ldc + col] = v;
            }
        }
    }
}

// ---------------------------------------------------------------------------
__global__ __launch_bounds__(256) void transpose_wh_cvt(
    const float* __restrict__ wh1, const float* __restrict__ wh2,
    half_t* __restrict__ o1, half_t* __restrict__ o2)
{
    __shared__ float tile[64][65];
    const int z = blockIdx.z;
    const float* src = (z < 4 ? wh1 : wh2) + (size_t)(z & 3) * 1024 * 1024;
    half_t*      dst = (z < 4 ? o1  : o2 ) + (size_t)(z & 3) * 1024 * 1024;
    const int kb = blockIdx.x * 64, nb = blockIdx.y * 64;
    const int t = threadIdx.x;
    #pragma unroll
    for (int i = 0; i < 16; ++i) {
        int idx = t + i*256, r = idx >> 6, c = idx & 63;
        tile[r][c] = src[(size_t)(kb + r)*1024 + nb + c];
    }
    __syncthreads();
    #pragma unroll
    for (int i = 0; i < 16; ++i) {
        int idx = t + i*256, r = idx >> 6, c = idx & 63;
        dst[(size_t)(nb + r)*1024 + kb + c] = (half_t)tile[c][r];
    }
}

// fc1_w (fp32 [1024][512]) -> fc1t (fp16 [512][1024])  (transpose + convert)
__global__ __launch_bounds__(256) void transpose_fc1(
    const float* __restrict__ fc1_w, half_t* __restrict__ fc1t)
{
    __shared__ float tile[64][65];
    const int hb = blockIdx.x * 64, ob = blockIdx.y * 64;   // grid (16, 8)
    const int t = threadIdx.x;
    #pragma unroll
    for (int i = 0; i < 16; ++i) {
        int idx = t + i*256, r = idx >> 6, c = idx & 63;
        tile[r][c] = fc1_w[(size_t)(hb + r)*512 + ob + c];
    }
    __syncthreads();
    #pragma unroll
    for (int i = 0; i < 16; ++i) {
        int idx = t + i*256, r = idx >> 6, c = idx & 63;
        fc1t[(size_t)(ob + r)*1024 + hb + c] = (half_t)tile[c][r];
    }
}

// b1x[j] = b1[j] + dot(wx1[j,:], fc1_b)   (fp32, j < 4096; one block per j)
__global__ __launch_bounds__(256) void fold_b1(
    const float* __restrict__ wx1, const float* __restrict__ fc1_b,
    const float* __restrict__ b1, float* __restrict__ b1x)
{
    __shared__ float sred[4];
    const int j = blockIdx.x, t = threadIdx.x;
    float4 wv = *(const float4*)&wx1[(size_t)j*1024 + t*4];
    float4 bv = *(const float4*)&fc1_b[t*4];
    float s = wv.x*bv.x + wv.y*bv.y + wv.z*bv.z + wv.w*bv.w;
    float tot = block_sum(s, sred);
    if (t == 0) b1x[j] = b1[j] + tot;
}

__global__ __launch_bounds__(256) void cvt_f32_f16(
    const float* __restrict__ in, half_t* __restrict__ out, int n8)
{
    int i = blockIdx.x * 256 + threadIdx.x;
    if (i >= n8) return;
    float4 lo = ((const float4*)in)[2*i];
    float4 hi = ((const float4*)in)[2*i + 1];
    union { uint4 v; half_t h[8]; } r;
    r.h[0]=(half_t)lo.x; r.h[1]=(half_t)lo.y; r.h[2]=(half_t)lo.z; r.h[3]=(half_t)lo.w;
    r.h[4]=(half_t)hi.x; r.h[5]=(half_t)hi.y; r.h[6]=(half_t)hi.z; r.h[7]=(half_t)hi.w;
    ((uint4*)out)[i] = r.v;
}

extern "C" void kernel_launch(void* const* d_in, const int* in_sizes, int n_in,
                              void* d_out, int out_size, void* d_ws, size_t ws_size,
                              hipStream_t stream)
{
    const float* obs   = (const float*)d_in[0];
    const float* fc1_w = (const float*)d_in[1];
    const float* fc1_b = (const float*)d_in[2];
    const float* wx1   = (const float*)d_in[3];
    const float* wh1   = (const float*)d_in[4];
    const float* b1    = (const float*)d_in[5];
    const float* wx2   = (const float*)d_in[6];
    const float* wh2   = (const float*)d_in[7];
    const float* b2    = (const float*)d_in[8];
    const float* fc2_w = (const float*)d_in[9];
    const float* fc2_b = (const float*)d_in[10];
    float* out = (float*)d_out;

    char* ws = (char*)d_ws;
    size_t off = 0;
    auto carve = [&](size_t bytes) -> char* {
        char* p = ws + off; off += (bytes + 255) & ~(size_t)255; return p;
    };
    half_t* wx1c  = (half_t*)carve((size_t)4096*1024*2);    //  8.4 MB
    half_t* wh1t  = (half_t*)carve((size_t)4096*1024*2);
    half_t* wx2c  = (half_t*)carve((size_t)4096*1024*2);
    half_t* wh2t  = (half_t*)carve((size_t)4096*1024*2);
    half_t* fc1t  = (half_t*)carve((size_t)512*1024*2);     //  1.0 MB
    half_t* W1x   = (half_t*)carve((size_t)4096*512*2);     //  4.2 MB
    half_t* fc2c  = (half_t*)carve((size_t)1024*1024*2);
    float*  b1x   = (float*) carve((size_t)4096*4);
    half_t* preA1 = (half_t*)carve((size_t)512*4096*2);     //  4.2 MB
    half_t* preA2 = (half_t*)carve((size_t)512*4096*2);
    half_t* preB1 = (half_t*)carve((size_t)512*4096*2);
    half_t* preB2 = (half_t*)carve((size_t)512*4096*2);
    half_t* h0s   = (half_t*)carve((size_t)512*1024*2);
    half_t* h1s   = (half_t*)carve((size_t)512*1024*2);
    float*  c0    = (float*) carve((size_t)512*1024*4);
    float*  c1    = (float*) carve((size_t)512*1024*4);

    hipMemsetAsync(h1s, 0, (size_t)512*1024*2, stream);     // h1(-1)=0 for z1@st0
    hipMemsetAsync(c0,  0, (size_t)512*1024*4, stream);
    hipMemsetAsync(c1,  0, (size_t)512*1024*4, stream);
    hipMemsetAsync(preB1, 0, (size_t)512*4096*2, stream);   // h0(-1)=0

    // one-time conversions + fc1 fold
    cvt_f32_f16<<<2048, 256, 0, stream>>>(wx1,   wx1c,  4*1024*1024/8);
    cvt_f32_f16<<<2048, 256, 0, stream>>>(wx2,   wx2c,  4*1024*1024/8);
    cvt_f32_f16<<<512,  256, 0, stream>>>(fc2_w, fc2c,  1024*1024/8);
    transpose_wh_cvt<<<dim3(16,16,8), 256, 0, stream>>>(wh1, wh2, wh1t, wh2t);
    transpose_fc1<<<dim3(16,8), 256, 0, stream>>>(fc1_w, fc1t);
    fold_b1<<<4096, 256, 0, stream>>>(wx1, fc1_b, b1, b1x);

    GArgs Z{};
    auto ga = [](const half_t* A, int lda, const half_t* B, int ldb, int K,
                 const float* bias, void* C, int ldc, int outhalf) {
        GArgs g; g.A=A; g.B=B; g.bias=bias; g.C=C;
        g.lda=lda; g.ldb=ldb; g.K=K; g.ldc=ldc; g.outhalf=outhalf; return g;
    };

    // W1x[4096][512] = wx1c @ fc1t^T  (M=4096, N=512, K=1024; A large -> rowpin)
    gemm_ms<<<128, 256, 0, stream>>>(
        ga(wx1c, 1024, fc1t, 1024, 1024, nullptr, W1x, 512, 1), Z, Z, 32, 4, 1, 1);
    // preA1(0) = obs(0) @ W1x^T  (st=-1: z3-only pass of the step kernel)
    step_gemm4<<<512, 256, 0, stream>>>(
        obs, W1x, wx2c, wh1t, wh2t,
        preA1, preA2, preB1, preB2, h0s, h1s, -1);

    for (int st = 0; st < 64; ++st) {
        cells_kernel<<<1024, 256, 0, stream>>>(
            preA1, preB1, preA2, preB2, b1x, b2,
            c0, c1, h0s, h1s, out, st);
        step_gemm4<<<512, 256, 0, stream>>>(
            obs, W1x, wx2c, wh1t, wh2t,
            preA1, preA2, preB1, preB2, h0s, h1s, st);
    }
    cells_final<<<512, 256, 0, stream>>>(preA2, preB2, b2, c1, h1s, out);

    // fc2: logit = h1 @ fc2_w^T + fc2_b -> d_out[0 : 512*1024) fp32
    gemm_ms<<<4*8, 256, 0, stream>>>(
        ga(h1s, 1024, fc2c, 1024, 1024, fc2_b, out, 1024, 0), Z, Z, 4, 8, 1, 0);
}